// Round 5
// baseline (185.051 us; speedup 1.0000x reference)
//
#include <hip/hip_runtime.h>
#include <math.h>

#define NDIMS 32
#define NANG 496          // 32*31/2
#define MPB 8             // matrices per gen_R block
#define CPT 2             // columns per thread in apply (f32x2 path)

typedef float f32x4 __attribute__((ext_vector_type(4)));
typedef float f32x2 __attribute__((ext_vector_type(2)));

// ---------------- Kernel 1: build R^T (mus folded) into workspace ----------
// RTbuf[m][k][i] = mus[m][i] * R[i][k]
__global__ __launch_bounds__(256)
void gen_R(const float* __restrict__ angles, const float* __restrict__ mus,
           float* __restrict__ RT)
{
    __shared__ float2 cs[MPB][NANG];      // 31744 B
    const int tid = threadIdx.x;
    const int m0  = blockIdx.x * MPB;

    for (int idx = tid; idx < MPB * NANG; idx += 256) {
        const int lm = idx / NANG, a = idx - lm * NANG;
        float sv, cv;
        sincosf(angles[(size_t)(m0 + lm) * NANG + a], &sv, &cv);
        cs[lm][a] = make_float2(cv, sv);
    }
    __syncthreads();

    const int lm = tid >> 5, j = tid & 31;   // lane j owns column j of mat[m]
    const int m  = m0 + lm;

    float r[NDIMS];
    #pragma unroll
    for (int i = 0; i < NDIMS; ++i) r[i] = (i == j) ? 1.0f : 0.0f;

    int sidx = 0;
    #pragma unroll
    for (int t = 0; t < NDIMS - 1; ++t) {
        #pragma unroll
        for (int b = t + 1; b < NDIMS; ++b) {
            const float2 v = cs[lm][sidx]; ++sidx;   // compile-time sidx
            const float c = v.x, sn = v.y;
            const float vt = r[t], vb = r[b];
            const float u  = sn * (vt + vb);
            r[t] = (c + sn) * vt - u;
            r[b] = (c - sn) * vb + u;
        }
    }

    float* dst = RT + (size_t)m * (NDIMS * NDIMS) + (size_t)j * NDIMS;
    const float* mu = mus + (size_t)m * NDIMS;
    #pragma unroll
    for (int i = 0; i < NDIMS; i += 4) {
        f32x4 v;
        v.x = r[i + 0] * mu[i + 0];
        v.y = r[i + 1] * mu[i + 1];
        v.z = r[i + 2] * mu[i + 2];
        v.w = r[i + 3] * mu[i + 3];
        *reinterpret_cast<f32x4*>(dst + i) = v;
    }
}

// ---------------- Kernel 2: out = R*x. R via SGPRs (scalar loads), no LDS --
// 2 cols/thread. Phase 1: 32 independent dwordx2 loads (16 KB MLP/wave).
// Phase 2: FMAs with R read as wave-uniform scalar loads -> SGPR operand.
// Phase 3: 32 dwordx2 stores (512 B contiguous per wave per row).
__global__ __launch_bounds__(256, 3)
void apply_R3(const float* __restrict__ x, const float* __restrict__ RT,
              float* __restrict__ out, int S)
{
    const int tid = threadIdx.x;
    const int m   = blockIdx.x;

    // wave-uniform base for this matrix: compiler emits s_load for rtm[...]
    const float* __restrict__ rtm = RT + (size_t)m * (NDIMS * NDIMS);

    const int col = blockIdx.y * (256 * CPT) + tid * CPT;   // exact fit: S % 512 == 0
    const float* xp = x   + (size_t)m * NDIMS * S + col;
    float*       op = out + (size_t)m * NDIMS * S + col;

    // phase 1: all 32 row-loads issued back-to-back, no consumers
    f32x2 xk[NDIMS];
    #pragma unroll
    for (int k = 0; k < NDIMS; ++k)
        xk[k] = *reinterpret_cast<const f32x2*>(xp + (size_t)k * S);

    f32x2 acc[NDIMS];
    #pragma unroll
    for (int i = 0; i < NDIMS; ++i) acc[i] = (f32x2)0.0f;

    // phase 2: R from scalar cache (SGPRs), x from VGPRs; contraction -> v_pk_fma
    #pragma unroll
    for (int k = 0; k < NDIMS; ++k) {
        const f32x2 xv = xk[k];
        #pragma unroll
        for (int i = 0; i < NDIMS; ++i) {
            acc[i] += rtm[k * NDIMS + i] * xv;   // uniform addr -> s_load, SGPR src
        }
    }

    // phase 3: stores
    #pragma unroll
    for (int i = 0; i < NDIMS; ++i)
        *reinterpret_cast<f32x2*>(op + (size_t)i * S) = acc[i];
}

// ---------------- Fallback: round-1 fused kernel (odd sizes / tiny ws) -----
#define RT_STRIDE 36
__global__ __launch_bounds__(256, 4)
void soot_fused(const float* __restrict__ x, const float* __restrict__ angles,
                const float* __restrict__ mus, float* __restrict__ out, int S)
{
    __shared__ float2 cs[NANG];
    __shared__ float  RT[NDIMS * RT_STRIDE];
    const int tid = threadIdx.x;
    const int m   = blockIdx.x;

    for (int s0 = tid; s0 < NANG; s0 += 256) {
        float sv, cv;
        sincosf(angles[(size_t)m * NANG + s0], &sv, &cv);
        cs[s0] = make_float2(cv, sv);
    }
    __syncthreads();

    if (tid < NDIMS) {
        const int j = tid;
        float r[NDIMS];
        #pragma unroll
        for (int i = 0; i < NDIMS; ++i) r[i] = (i == j) ? 1.0f : 0.0f;
        int sidx = 0;
        #pragma unroll
        for (int t = 0; t < NDIMS - 1; ++t)
            #pragma unroll
            for (int b = t + 1; b < NDIMS; ++b) {
                const float2 v = cs[sidx]; ++sidx;
                const float c = v.x, sn = v.y;
                const float vt = r[t], vb = r[b];
                const float u  = sn * (vt + vb);
                r[t] = (c + sn) * vt - u;
                r[b] = (c - sn) * vb + u;
            }
        #pragma unroll
        for (int i = 0; i < NDIMS; ++i)
            RT[j * RT_STRIDE + i] = r[i] * mus[(size_t)m * NDIMS + i];
    }
    __syncthreads();

    for (int c0 = tid; c0 < S; c0 += 256) {
        float acc[NDIMS];
        #pragma unroll
        for (int i = 0; i < NDIMS; ++i) acc[i] = 0.f;
        #pragma unroll
        for (int k = 0; k < NDIMS; ++k) {
            const float xv = x[(size_t)m * NDIMS * S + (size_t)k * S + c0];
            #pragma unroll
            for (int i = 0; i < NDIMS; ++i)
                acc[i] = fmaf(RT[k * RT_STRIDE + i], xv, acc[i]);
        }
        #pragma unroll
        for (int i = 0; i < NDIMS; ++i)
            out[(size_t)m * NDIMS * S + (size_t)i * S + c0] = acc[i];
    }
}

extern "C" void kernel_launch(void* const* d_in, const int* in_sizes, int n_in,
                              void* d_out, int out_size, void* d_ws, size_t ws_size,
                              hipStream_t stream) {
    const float* x      = (const float*)d_in[0];
    const float* angles = (const float*)d_in[1];
    const float* mus    = (const float*)d_in[2];
    float* out          = (float*)d_out;

    const int M = in_sizes[1] / NANG;              // 1024
    const int S = in_sizes[0] / (M * NDIMS);       // 2048

    const size_t rt_bytes = (size_t)M * NDIMS * NDIMS * sizeof(float);  // 4 MB
    const int cols_per_block = 256 * CPT;          // 512
    if (ws_size >= rt_bytes && (M % MPB) == 0 && (S % cols_per_block) == 0) {
        float* RT = (float*)d_ws;
        gen_R<<<dim3(M / MPB), 256, 0, stream>>>(angles, mus, RT);
        dim3 grid(M, S / cols_per_block);
        apply_R3<<<grid, 256, 0, stream>>>(x, RT, out, S);
    } else {
        soot_fused<<<dim3(M), 256, 0, stream>>>(x, angles, mus, out, S);
    }
}